// Round 3
// baseline (944.744 us; speedup 1.0000x reference)
//
#include <hip/hip_runtime.h>
#include <hip/hip_bf16.h>
#include <math.h>

// Problem: B=2, S=2048, D=1024, H=16, Hd=64. fp32 in/out.
constexpr int Bt   = 2;
constexpr int Sseq = 2048;
constexpr int Dm   = 1024;
constexpr int Hh   = 16;
constexpr int HdC  = 64;
constexpr int Mrows = Bt * Sseq;   // 4096
constexpr int Kd    = 1024;        // contraction dim for both GEMMs

typedef __attribute__((ext_vector_type(8))) short bf16x8;   // MFMA A/B frag (8 bf16)
typedef __attribute__((ext_vector_type(4))) float f32x4;    // MFMA C/D frag

__device__ __forceinline__ ushort bfhi(float x) {
    __hip_bfloat16 h = __float2bfloat16(x);
    return *reinterpret_cast<ushort*>(&h);
}
__device__ __forceinline__ float bf2f(ushort u) {
    __hip_bfloat16 h;
    *reinterpret_cast<ushort*>(&h) = u;
    return __bfloat162float(h);
}

// ============================================================================
// bf16x2 MFMA GEMM with in-register split: C[m][j] = sum_k A[m][k]*W[j][k] + b[j]
//   A (fp32, MrowsxKd) and W (fp32, row-major [j][k]) are loaded as fp32,
//   split in registers into hi/lo bf16, staged to LDS, and combined with the
//   3-term rule  Ahi*Whi + Ahi*Wlo + Alo*Whi  (rel err ~2^-16).
// Tile 128x128, BK=32, 4 waves (2x2), wave = 64x64 = 4x4 frags of 16x16x32.
// LDS row = 128B = 8 slots x 16B: logical slots 0..3 = hi k-chunks (8 bf16 each),
// 4..7 = lo. Physical slot p holds logical slot p^(row&7) (XOR swizzle, applied
// identically on write and read -> bank-group = slot -> conflict-free b128 ops).
// ============================================================================
__global__ __launch_bounds__(256)
void gemm_bf16x2(const float* __restrict__ A,
                 const float* __restrict__ W0, const float* __restrict__ W1,
                 const float* __restrict__ W2,
                 const float* __restrict__ b0, const float* __restrict__ b1,
                 const float* __restrict__ b2,
                 float* __restrict__ C, int Dout)
{
    __shared__ alignas(16) ushort As[128 * 64];   // [row][64 ushorts] = 16 KiB
    __shared__ alignas(16) ushort Bs[128 * 64];

    const int tid = threadIdx.x, lane = tid & 63, w = tid >> 6;

    // XCD-aware bijective block swizzle (grids here are multiples of 8).
    const int gx = gridDim.x;
    int bid = blockIdx.y * gx + blockIdx.x;
    int cpx = (gx * gridDim.y) >> 3;
    int sb  = (bid & 7) * cpx + (bid >> 3);
    const int m0 = (sb / gx) * 128;
    const int j0 = (sb % gx) * 128;

    const int wsel = j0 >> 10;   // weight/bias slab for fused QKV (Dout=3072)
    const float* __restrict__ W    = (wsel == 0) ? W0 : ((wsel == 1) ? W1 : W2);
    const float* __restrict__ bias = (wsel == 0) ? b0 : ((wsel == 1) ? b1 : b2);
    const int jj0 = j0 & 1023;

    const int wr = w >> 1, wc = w & 1;          // wave's 64x64 sub-tile
    const int rl = lane & 15, kq = lane >> 4;   // frag row-in-16 / k-quarter
    const int sw0 = rl & 7;                     // read-side swizzle key (row&7)

    // Staging assignment: thread -> (row, k-half). 2 threads cover one row's 32 k.
    const int srow  = tid >> 1;   // 0..127
    const int khalf = tid & 1;    // 0: k 0..15, 1: k 16..31
    const int rsw   = srow & 7;   // write-side swizzle key

    f32x4 acc[4][4] = {};

    for (int k0 = 0; k0 < Kd; k0 += 32) {
        __syncthreads();   // previous step's frag reads done before overwrite

        // ---- stage: fp32 global -> reg split -> swizzled LDS ----
        {
            const float* ga = A + (size_t)(m0  + srow) * Kd + k0 + khalf * 16;
            const float* gb = W + (size_t)(jj0 + srow) * Kd + k0 + khalf * 16;
            float av[16], bv[16];
            #pragma unroll
            for (int p = 0; p < 4; ++p) {
                *(float4*)&av[p * 4] = *(const float4*)(ga + p * 4);
                *(float4*)&bv[p * 4] = *(const float4*)(gb + p * 4);
            }
            ushort* pa = As + srow * 64;
            ushort* pb = Bs + srow * 64;
            #pragma unroll
            for (int t = 0; t < 2; ++t) {        // two 8-element k-chunks
                bf16x8 hia, loa, hib, lob;
                #pragma unroll
                for (int e = 0; e < 8; ++e) {
                    float xa = av[t * 8 + e], xb = bv[t * 8 + e];
                    ushort ha = bfhi(xa), hb = bfhi(xb);
                    hia[e] = (short)ha; loa[e] = (short)bfhi(xa - bf2f(ha));
                    hib[e] = (short)hb; lob[e] = (short)bfhi(xb - bf2f(hb));
                }
                int s = khalf * 2 + t;           // logical hi slot 0..3
                *(bf16x8*)(pa + ((s    ) ^ rsw) * 8) = hia;
                *(bf16x8*)(pa + ((s + 4) ^ rsw) * 8) = loa;
                *(bf16x8*)(pb + ((s    ) ^ rsw) * 8) = hib;
                *(bf16x8*)(pb + ((s + 4) ^ rsw) * 8) = lob;
            }
        }
        __syncthreads();

        // ---- fragments: swizzled ds_read_b128 ----
        bf16x8 ah[4], al[4], bh[4], bl[4];
        #pragma unroll
        for (int i = 0; i < 4; ++i) {
            const ushort* pa = As + (wr * 64 + i * 16 + rl) * 64;
            ah[i] = *(const bf16x8*)(pa + ((kq    ) ^ sw0) * 8);
            al[i] = *(const bf16x8*)(pa + ((kq + 4) ^ sw0) * 8);
            const ushort* pb = Bs + (wc * 64 + i * 16 + rl) * 64;
            bh[i] = *(const bf16x8*)(pb + ((kq    ) ^ sw0) * 8);
            bl[i] = *(const bf16x8*)(pb + ((kq + 4) ^ sw0) * 8);
        }

        // ---- 48 MFMA: 3-term split product ----
        #pragma unroll
        for (int i = 0; i < 4; ++i)
            #pragma unroll
            for (int j = 0; j < 4; ++j) {
                acc[i][j] = __builtin_amdgcn_mfma_f32_16x16x32_bf16(ah[i], bh[j], acc[i][j], 0, 0, 0);
                acc[i][j] = __builtin_amdgcn_mfma_f32_16x16x32_bf16(ah[i], bl[j], acc[i][j], 0, 0, 0);
                acc[i][j] = __builtin_amdgcn_mfma_f32_16x16x32_bf16(al[i], bh[j], acc[i][j], 0, 0, 0);
            }
    }

    // ---- epilogue: C/D layout col=lane&15, row=(lane>>4)*4+reg [m89] ----
    #pragma unroll
    for (int i = 0; i < 4; ++i)
        #pragma unroll
        for (int j = 0; j < 4; ++j) {
            int col = j0 + wc * 64 + j * 16 + rl;
            float bv = bias[col & 1023];
            #pragma unroll
            for (int r = 0; r < 4; ++r) {
                int row = m0 + wr * 64 + i * 16 + kq * 4 + r;
                C[(size_t)row * Dout + col] = acc[i][j][r] + bv;
            }
        }
}

// ============================================================================
// Flash-style causal attention, fp32 (round-1 structure, re-audited).
// qkv: [Mrows][3072], cols [0,1024)=Q, [1024,2048)=K, [2048,3072)=V.
// out: [Mrows][1024], head h at cols [h*64, h*64+64).
// ============================================================================
constexpr int BQ = 64, BKV = 64, LPAD = 4;
constexpr float SM_SCALE = 0.125f;   // 1/sqrt(64)

__global__ __launch_bounds__(256)
void attn_causal(const float* __restrict__ qkv, float* __restrict__ aout)
{
    const int qt = blockIdx.x, h = blockIdx.y, b = blockIdx.z;
    const int q0 = qt * BQ;
    const int tid = threadIdx.x;
    const int tx = tid & 15, ty = tid >> 4;

    __shared__ float Qt[HdC][BQ + LPAD];
    __shared__ float Kt[HdC][BKV + LPAD];
    __shared__ float Vs[BKV][HdC + LPAD];
    __shared__ float Pt[BKV][BQ + LPAD];

    {
        const size_t rowbase = (size_t)(b * Sseq + q0);
        #pragma unroll
        for (int p = 0; p < 16; ++p) {
            int idx = tid + p * 256;
            int d = idx & 63, r = idx >> 6;
            Qt[d][r] = qkv[(rowbase + r) * 3072 + h * 64 + d] * SM_SCALE;
        }
    }

    float m_i[4], l_i[4];
    #pragma unroll
    for (int i = 0; i < 4; ++i) { m_i[i] = -INFINITY; l_i[i] = 0.0f; }
    float accO[4][4] = {};

    for (int kt = 0; kt <= qt; ++kt) {
        const int k0 = kt * BKV;
        __syncthreads();   // protect Kt/Vs/Pt (and first-use Qt) before overwrite
        {
            const size_t rowbase = (size_t)(b * Sseq + k0);
            #pragma unroll
            for (int p = 0; p < 16; ++p) {
                int idx = tid + p * 256;
                int d = idx & 63, r = idx >> 6;
                Kt[d][r] = qkv[(rowbase + r) * 3072 + 1024 + h * 64 + d];
            }
            #pragma unroll
            for (int p = 0; p < 4; ++p) {
                int idx = tid + p * 256;
                int c4 = idx & 15, r = idx >> 4;
                *(float4*)&Vs[r][c4 * 4] =
                    *(const float4*)&qkv[(rowbase + r) * 3072 + 2048 + h * 64 + c4 * 4];
            }
        }
        __syncthreads();

        float sc[4][4] = {};
        #pragma unroll 16
        for (int d = 0; d < HdC; ++d) {
            float4 qv = *(const float4*)&Qt[d][ty * 4];
            float4 kv = *(const float4*)&Kt[d][tx * 4];
            float q_[4] = {qv.x, qv.y, qv.z, qv.w};
            float k_[4] = {kv.x, kv.y, kv.z, kv.w};
            #pragma unroll
            for (int i = 0; i < 4; ++i)
                #pragma unroll
                for (int j = 0; j < 4; ++j)
                    sc[i][j] = fmaf(q_[i], k_[j], sc[i][j]);
        }

        if (kt == qt) {   // causal mask only on the diagonal tile
            #pragma unroll
            for (int i = 0; i < 4; ++i)
                #pragma unroll
                for (int j = 0; j < 4; ++j)
                    if (k0 + tx * 4 + j > q0 + ty * 4 + i) sc[i][j] = -INFINITY;
        }

        // Online softmax; row state replicated across the 16-lane tx group.
        float mnew[4], fscale[4];
        #pragma unroll
        for (int i = 0; i < 4; ++i) {
            float v = fmaxf(fmaxf(sc[i][0], sc[i][1]), fmaxf(sc[i][2], sc[i][3]));
            v = fmaxf(v, __shfl_xor(v, 1));
            v = fmaxf(v, __shfl_xor(v, 2));
            v = fmaxf(v, __shfl_xor(v, 4));
            v = fmaxf(v, __shfl_xor(v, 8));
            mnew[i]   = fmaxf(m_i[i], v);
            fscale[i] = __expf(m_i[i] - mnew[i]);  // exp(-inf)=0 on first tile
            m_i[i]    = mnew[i];
        }

        #pragma unroll
        for (int i = 0; i < 4; ++i) {
            float s = 0.0f;
            #pragma unroll
            for (int j = 0; j < 4; ++j) {
                float p = __expf(sc[i][j] - mnew[i]);
                Pt[tx * 4 + j][ty * 4 + i] = p;
                s += p;
            }
            s += __shfl_xor(s, 1);
            s += __shfl_xor(s, 2);
            s += __shfl_xor(s, 4);
            s += __shfl_xor(s, 8);
            l_i[i] = l_i[i] * fscale[i] + s;
        }
        __syncthreads();   // Pt ready

        #pragma unroll
        for (int i = 0; i < 4; ++i)
            #pragma unroll
            for (int j = 0; j < 4; ++j)
                accO[i][j] *= fscale[i];
        #pragma unroll 16
        for (int k = 0; k < BKV; ++k) {
            float4 pv = *(const float4*)&Pt[k][ty * 4];
            float4 vv = *(const float4*)&Vs[k][tx * 4];
            float p_[4] = {pv.x, pv.y, pv.z, pv.w};
            float v_[4] = {vv.x, vv.y, vv.z, vv.w};
            #pragma unroll
            for (int i = 0; i < 4; ++i)
                #pragma unroll
                for (int j = 0; j < 4; ++j)
                    accO[i][j] = fmaf(p_[i], v_[j], accO[i][j]);
        }
    }

    #pragma unroll
    for (int i = 0; i < 4; ++i) {
        float inv = 1.0f / l_i[i];
        int q = q0 + ty * 4 + i;
        float4 o = { accO[i][0] * inv, accO[i][1] * inv,
                     accO[i][2] * inv, accO[i][3] * inv };
        *(float4*)&aout[(size_t)(b * Sseq + q) * Dm + h * 64 + tx * 4] = o;
    }
}

// ============================================================================
extern "C" void kernel_launch(void* const* d_in, const int* in_sizes, int n_in,
                              void* d_out, int out_size, void* d_ws, size_t ws_size,
                              hipStream_t stream)
{
    const float* x  = (const float*)d_in[0];
    const float* wq = (const float*)d_in[1];
    const float* bq = (const float*)d_in[2];
    const float* wk = (const float*)d_in[3];
    const float* bk = (const float*)d_in[4];
    const float* wv = (const float*)d_in[5];
    const float* bv = (const float*)d_in[6];
    const float* wo = (const float*)d_in[7];
    const float* bo = (const float*)d_in[8];
    float* out = (float*)d_out;

    const size_t NEED = (size_t)Mrows * 3072 * 4 + (size_t)Mrows * Dm * 4; // 64 MiB
    if (ws_size < NEED) return;   // cannot run without scratch; fail verification cleanly

    float* qkv  = (float*)d_ws;                  // [4096][3072] fp32 = 48 MiB
    float* attn = qkv + (size_t)Mrows * 3072;    // [4096][1024] fp32 = 16 MiB

    // Fused QKV projection (Dout=3072; slabs select wq/wk/wv).
    gemm_bf16x2<<<dim3(24, 32), 256, 0, stream>>>(
        x, wq, wk, wv, bq, bk, bv, qkv, 3072);

    // Causal multi-head attention (fp32).
    attn_causal<<<dim3(Sseq / BQ, Hh, Bt), 256, 0, stream>>>(qkv, attn);

    // Output projection (Dout=1024).
    gemm_bf16x2<<<dim3(8, 32), 256, 0, stream>>>(
        attn, wo, wo, wo, bo, bo, bo, out, 1024);
}

// Round 4
// 538.442 us; speedup vs baseline: 1.7546x; 1.7546x over previous
//
#include <hip/hip_runtime.h>
#include <hip/hip_bf16.h>
#include <math.h>

// Problem: B=2, S=2048, D=1024, H=16, Hd=64. fp32 in/out.
constexpr int Bt   = 2;
constexpr int Sseq = 2048;
constexpr int Dm   = 1024;
constexpr int Hh   = 16;
constexpr int Mrows = Bt * Sseq;   // 4096
constexpr int Kd    = 1024;        // contraction dim for both GEMMs

typedef __attribute__((ext_vector_type(8))) short bf16x8;   // MFMA A/B frag
typedef __attribute__((ext_vector_type(4))) float f32x4;    // MFMA C/D frag

__device__ __forceinline__ ushort bfhi(float x) {
    __hip_bfloat16 h = __float2bfloat16(x);
    return *reinterpret_cast<ushort*>(&h);
}
__device__ __forceinline__ float bf2f(ushort u) {
    __hip_bfloat16 h;
    *reinterpret_cast<ushort*>(&h) = u;
    return __bfloat162float(h);
}
__device__ __forceinline__ void split2(float x, ushort& h, ushort& l) {
    h = bfhi(x);
    l = bfhi(x - bf2f(h));
}

// ============================================================================
// bf16x2 MFMA GEMM (verified round 3): C = A*W^T + bias, 3-term split.
// Tile 128x128, BK=32, 4 waves 2x2, wave 64x64 = 4x4 frags of 16x16x32.
// MODE 0: fused QKV. Writes split planes:
//   Q slab (col<1024):   (val)*0.125 -> qk_hi/lo[token][col]
//   K slab (col<2048):   val -> qk_hi/lo[token][col]
//   V slab:              val -> vt_hi/lo[(b*16+h)*64+d][token&2047] (transposed)
// MODE 1: fp32 epilogue -> Cf[token][1024] (output projection).
// ============================================================================
template<int MODE>
__global__ __launch_bounds__(256)
void gemm_bf16x2(const float* __restrict__ A,
                 const float* __restrict__ W0, const float* __restrict__ W1,
                 const float* __restrict__ W2,
                 const float* __restrict__ b0, const float* __restrict__ b1,
                 const float* __restrict__ b2,
                 float* __restrict__ Cf,
                 ushort* __restrict__ qk_hi, ushort* __restrict__ qk_lo,
                 ushort* __restrict__ vt_hi, ushort* __restrict__ vt_lo)
{
    __shared__ alignas(16) ushort As[128 * 64];
    __shared__ alignas(16) ushort Bs[128 * 64];

    const int tid = threadIdx.x, lane = tid & 63, w = tid >> 6;

    const int gx = gridDim.x;
    int bid = blockIdx.y * gx + blockIdx.x;
    int cpx = (gx * gridDim.y) >> 3;
    int sb  = (bid & 7) * cpx + (bid >> 3);
    const int m0 = (sb / gx) * 128;
    const int j0 = (sb % gx) * 128;

    const int wsel = j0 >> 10;
    const float* __restrict__ W    = (wsel == 0) ? W0 : ((wsel == 1) ? W1 : W2);
    const float* __restrict__ bias = (wsel == 0) ? b0 : ((wsel == 1) ? b1 : b2);
    const int jj0 = j0 & 1023;

    const int wr = w >> 1, wc = w & 1;
    const int rl = lane & 15, kq = lane >> 4;
    const int sw0 = rl & 7;

    const int srow  = tid >> 1;
    const int khalf = tid & 1;
    const int rsw   = srow & 7;

    f32x4 acc[4][4] = {};

    for (int k0 = 0; k0 < Kd; k0 += 32) {
        __syncthreads();
        {
            const float* ga = A + (size_t)(m0  + srow) * Kd + k0 + khalf * 16;
            const float* gb = W + (size_t)(jj0 + srow) * Kd + k0 + khalf * 16;
            float av[16], bv[16];
            #pragma unroll
            for (int p = 0; p < 4; ++p) {
                *(float4*)&av[p * 4] = *(const float4*)(ga + p * 4);
                *(float4*)&bv[p * 4] = *(const float4*)(gb + p * 4);
            }
            ushort* pa = As + srow * 64;
            ushort* pb = Bs + srow * 64;
            #pragma unroll
            for (int t = 0; t < 2; ++t) {
                bf16x8 hia, loa, hib, lob;
                #pragma unroll
                for (int e = 0; e < 8; ++e) {
                    float xa = av[t * 8 + e], xb = bv[t * 8 + e];
                    ushort ha, la, hb, lb;
                    split2(xa, ha, la); split2(xb, hb, lb);
                    hia[e] = (short)ha; loa[e] = (short)la;
                    hib[e] = (short)hb; lob[e] = (short)lb;
                }
                int s = khalf * 2 + t;
                *(bf16x8*)(pa + ((s    ) ^ rsw) * 8) = hia;
                *(bf16x8*)(pa + ((s + 4) ^ rsw) * 8) = loa;
                *(bf16x8*)(pb + ((s    ) ^ rsw) * 8) = hib;
                *(bf16x8*)(pb + ((s + 4) ^ rsw) * 8) = lob;
            }
        }
        __syncthreads();

        bf16x8 ah[4], al[4], bh[4], bl[4];
        #pragma unroll
        for (int i = 0; i < 4; ++i) {
            const ushort* pa = As + (wr * 64 + i * 16 + rl) * 64;
            ah[i] = *(const bf16x8*)(pa + ((kq    ) ^ sw0) * 8);
            al[i] = *(const bf16x8*)(pa + ((kq + 4) ^ sw0) * 8);
            const ushort* pb = Bs + (wc * 64 + i * 16 + rl) * 64;
            bh[i] = *(const bf16x8*)(pb + ((kq    ) ^ sw0) * 8);
            bl[i] = *(const bf16x8*)(pb + ((kq + 4) ^ sw0) * 8);
        }
        #pragma unroll
        for (int i = 0; i < 4; ++i)
            #pragma unroll
            for (int j = 0; j < 4; ++j) {
                acc[i][j] = __builtin_amdgcn_mfma_f32_16x16x32_bf16(ah[i], bh[j], acc[i][j], 0, 0, 0);
                acc[i][j] = __builtin_amdgcn_mfma_f32_16x16x32_bf16(ah[i], bl[j], acc[i][j], 0, 0, 0);
                acc[i][j] = __builtin_amdgcn_mfma_f32_16x16x32_bf16(al[i], bh[j], acc[i][j], 0, 0, 0);
            }
    }

    // Epilogue. C/D: col=lane&15, row=(lane>>4)*4+reg (verified r3).
    #pragma unroll
    for (int i = 0; i < 4; ++i)
        #pragma unroll
        for (int j = 0; j < 4; ++j) {
            int col = j0 + wc * 64 + j * 16 + rl;
            float bv = bias[col & 1023];
            int token0 = m0 + wr * 64 + i * 16 + kq * 4;
            if constexpr (MODE == 1) {
                #pragma unroll
                for (int r = 0; r < 4; ++r)
                    Cf[(size_t)(token0 + r) * 1024 + col] = acc[i][j][r] + bv;
            } else {
                if (col < 2048) {   // Q or K slab (wave-uniform per frag)
                    float scale = (col < 1024) ? 0.125f : 1.0f;
                    #pragma unroll
                    for (int r = 0; r < 4; ++r) {
                        float val = (acc[i][j][r] + bv) * scale;
                        ushort hs, ls;
                        split2(val, hs, ls);
                        size_t idx = (size_t)(token0 + r) * 2048 + col;
                        qk_hi[idx] = hs;
                        qk_lo[idx] = ls;
                    }
                } else {            // V slab -> transposed planes
                    int cc = col - 2048;
                    int hh = cc >> 6, dd = cc & 63;
                    int bb = token0 >> 11, s0 = token0 & 2047;
                    ushort hs[4], ls[4];
                    #pragma unroll
                    for (int r = 0; r < 4; ++r)
                        split2(acc[i][j][r] + bv, hs[r], ls[r]);
                    size_t vrow = ((size_t)(bb * 16 + hh) * 64 + dd) * 2048 + s0;
                    *(ushort4*)(vt_hi + vrow) = make_ushort4(hs[0], hs[1], hs[2], hs[3]);
                    *(ushort4*)(vt_lo + vrow) = make_ushort4(ls[0], ls[1], ls[2], ls[3]);
                }
            }
        }
}

// ============================================================================
// MFMA flash attention, bf16x2 3-term everywhere, fp32 softmax state.
// Block: 128 q-rows, 4 waves (strip of 32 q each), KV tiles of 64.
// Q frags in registers (direct global). K/V staged to XOR-swizzled LDS.
// P split hi/lo, round-tripped through chunk-swizzled LDS (A-operand).
// LDS: 4*8KB (K/V hi/lo) + 32KB (P) = 64KB -> 2 blocks/CU.
// ============================================================================
__global__ __launch_bounds__(256)
void attn_mfma(const ushort* __restrict__ qk_hi, const ushort* __restrict__ qk_lo,
               const ushort* __restrict__ vt_hi, const ushort* __restrict__ vt_lo,
               float* __restrict__ aout)
{
    __shared__ alignas(16) ushort Kh[4096], Kl[4096], Vh[4096], Vl[4096];
    __shared__ alignas(16) uint   P32[4][2048];   // per-wave [32 q][64 kv], chunk-swizzled

    const int qt = gridDim.x - 1 - blockIdx.x;   // big blocks first
    const int h  = blockIdx.y, b = blockIdx.z;
    const int q0 = qt * 128;
    const int tid = threadIdx.x, lane = tid & 63, w = tid >> 6;
    const int rl = lane & 15, kq = lane >> 4;

    // ---- Q fragments: direct global -> regs (once per block) ----
    bf16x8 qfh[2][2], qfl[2][2];   // [m-frag][k-step]
    {
        const size_t qrow = (size_t)(b * Sseq + q0 + w * 32);
        #pragma unroll
        for (int mi = 0; mi < 2; ++mi)
            #pragma unroll
            for (int s = 0; s < 2; ++s) {
                size_t g = (qrow + mi * 16 + rl) * 2048 + h * 64 + s * 32 + kq * 8;
                qfh[mi][s] = *(const bf16x8*)(qk_hi + g);
                qfl[mi][s] = *(const bf16x8*)(qk_lo + g);
            }
    }

    f32x4 accO[2][4] = {};          // [m-frag][n-frag over d]
    float m_i[2][4], l_i[2][4];
    #pragma unroll
    for (int mi = 0; mi < 2; ++mi)
        #pragma unroll
        for (int r = 0; r < 4; ++r) { m_i[mi][r] = -INFINITY; l_i[mi][r] = 0.0f; }

    const int NT = 2 * qt + 2;
    for (int kt = 0; kt < NT; ++kt) {
        const int kv0 = kt * 64;
        __syncthreads();   // all waves done reading K/V frags of prev tile
        {   // stage K,V hi/lo (4 planes x 8KB), reg -> swizzled LDS
            int row = tid >> 2, c2 = tid & 3;
            size_t gk = (size_t)(b * Sseq + kv0 + row) * 2048 + 1024 + h * 64 + c2 * 16;
            size_t gv = ((size_t)((b * 16 + h) * 64) + row) * 2048 + kv0 + c2 * 16;
            #pragma unroll
            for (int half = 0; half < 2; ++half) {
                int sw = (c2 * 2 + half) ^ (row & 7);
                *(bf16x8*)(Kh + row * 64 + sw * 8) = *(const bf16x8*)(qk_hi + gk + half * 8);
                *(bf16x8*)(Kl + row * 64 + sw * 8) = *(const bf16x8*)(qk_lo + gk + half * 8);
                *(bf16x8*)(Vh + row * 64 + sw * 8) = *(const bf16x8*)(vt_hi + gv + half * 8);
                *(bf16x8*)(Vl + row * 64 + sw * 8) = *(const bf16x8*)(vt_lo + gv + half * 8);
            }
        }
        __syncthreads();

        // ---- scores: S = Q K^T (3-term), per wave 32q x 64kv ----
        f32x4 sc[2][4] = {};
        #pragma unroll
        for (int s = 0; s < 2; ++s) {
            bf16x8 kh[4], kl[4];
            #pragma unroll
            for (int n = 0; n < 4; ++n) {
                int row = n * 16 + rl;
                int sw = (s * 4 + kq) ^ (row & 7);
                kh[n] = *(const bf16x8*)(Kh + row * 64 + sw * 8);
                kl[n] = *(const bf16x8*)(Kl + row * 64 + sw * 8);
            }
            #pragma unroll
            for (int mi = 0; mi < 2; ++mi)
                #pragma unroll
                for (int n = 0; n < 4; ++n) {
                    sc[mi][n] = __builtin_amdgcn_mfma_f32_16x16x32_bf16(qfh[mi][s], kh[n], sc[mi][n], 0, 0, 0);
                    sc[mi][n] = __builtin_amdgcn_mfma_f32_16x16x32_bf16(qfh[mi][s], kl[n], sc[mi][n], 0, 0, 0);
                    sc[mi][n] = __builtin_amdgcn_mfma_f32_16x16x32_bf16(qfl[mi][s], kh[n], sc[mi][n], 0, 0, 0);
                }
        }

        // ---- causal mask (only near-diagonal tiles) ----
        if (kt >= 2 * qt) {
            #pragma unroll
            for (int mi = 0; mi < 2; ++mi)
                #pragma unroll
                for (int n = 0; n < 4; ++n)
                    #pragma unroll
                    for (int r = 0; r < 4; ++r)
                        if (kv0 + n * 16 + rl > q0 + w * 32 + mi * 16 + kq * 4 + r)
                            sc[mi][n][r] = -INFINITY;
        }

        // ---- online softmax (rows = kq*4+r per m-frag; cols across rl) ----
        float fs[2][4];
        #pragma unroll
        for (int mi = 0; mi < 2; ++mi)
            #pragma unroll
            for (int r = 0; r < 4; ++r) {
                float v = fmaxf(fmaxf(sc[mi][0][r], sc[mi][1][r]),
                                fmaxf(sc[mi][2][r], sc[mi][3][r]));
                v = fmaxf(v, __shfl_xor(v, 1));
                v = fmaxf(v, __shfl_xor(v, 2));
                v = fmaxf(v, __shfl_xor(v, 4));
                v = fmaxf(v, __shfl_xor(v, 8));
                float mnew = fmaxf(m_i[mi][r], v);
                fs[mi][r]  = __expf(m_i[mi][r] - mnew);
                m_i[mi][r] = mnew;
            }

        // ---- P = exp(sc - m): split hi/lo -> swizzled LDS; row-sum ----
        #pragma unroll
        for (int mi = 0; mi < 2; ++mi)
            #pragma unroll
            for (int r = 0; r < 4; ++r) {
                int q = mi * 16 + kq * 4 + r;
                float sum = 0.0f;
                #pragma unroll
                for (int n = 0; n < 4; ++n) {
                    float p = __expf(sc[mi][n][r] - m_i[mi][r]);
                    sum += p;
                    ushort hs, ls;
                    split2(p, hs, ls);
                    int c = n * 4 + (rl >> 2);
                    P32[w][q * 64 + ((c ^ (q & 7)) << 2) + (rl & 3)] =
                        (uint)hs | ((uint)ls << 16);
                }
                sum += __shfl_xor(sum, 1);
                sum += __shfl_xor(sum, 2);
                sum += __shfl_xor(sum, 4);
                sum += __shfl_xor(sum, 8);
                l_i[mi][r] = l_i[mi][r] * fs[mi][r] + sum;
            }

        // ---- rescale O, then O += P V (3-term) ----
        #pragma unroll
        for (int mi = 0; mi < 2; ++mi)
            #pragma unroll
            for (int n = 0; n < 4; ++n)
                #pragma unroll
                for (int r = 0; r < 4; ++r)
                    accO[mi][n][r] *= fs[mi][r];

        #pragma unroll
        for (int s2 = 0; s2 < 2; ++s2) {   // kv k-steps
            bf16x8 vh[4], vl[4];
            #pragma unroll
            for (int n = 0; n < 4; ++n) {
                int row = n * 16 + rl;
                int sw = (s2 * 4 + kq) ^ (row & 7);
                vh[n] = *(const bf16x8*)(Vh + row * 64 + sw * 8);
                vl[n] = *(const bf16x8*)(Vl + row * 64 + sw * 8);
            }
            #pragma unroll
            for (int mi = 0; mi < 2; ++mi) {
                // P A-frag: q=rl row, kv chunk (s2,kq); two swizzled 16B reads
                uint u[8];
                #pragma unroll
                for (int cc = 0; cc < 2; ++cc) {
                    int c = s2 * 8 + kq * 2 + cc;
                    const uint* pp = &P32[w][(mi * 16 + rl) * 64 + ((c ^ (rl & 7)) << 2)];
                    uint4 uu = *(const uint4*)pp;
                    u[cc * 4 + 0] = uu.x; u[cc * 4 + 1] = uu.y;
                    u[cc * 4 + 2] = uu.z; u[cc * 4 + 3] = uu.w;
                }
                uint tph[4], tpl[4];
                #pragma unroll
                for (int jw = 0; jw < 4; ++jw) {
                    tph[jw] = (u[2 * jw] & 0xffffu) | (u[2 * jw + 1] << 16);
                    tpl[jw] = (u[2 * jw] >> 16) | (u[2 * jw + 1] & 0xffff0000u);
                }
                bf16x8 ph = *reinterpret_cast<bf16x8*>(tph);
                bf16x8 pl = *reinterpret_cast<bf16x8*>(tpl);
                #pragma unroll
                for (int n = 0; n < 4; ++n) {
                    accO[mi][n] = __builtin_amdgcn_mfma_f32_16x16x32_bf16(ph, vh[n], accO[mi][n], 0, 0, 0);
                    accO[mi][n] = __builtin_amdgcn_mfma_f32_16x16x32_bf16(ph, vl[n], accO[mi][n], 0, 0, 0);
                    accO[mi][n] = __builtin_amdgcn_mfma_f32_16x16x32_bf16(pl, vh[n], accO[mi][n], 0, 0, 0);
                }
            }
        }
    }

    // ---- epilogue: divide by l, write fp32 [token][1024] ----
    #pragma unroll
    for (int mi = 0; mi < 2; ++mi)
        #pragma unroll
        for (int r = 0; r < 4; ++r) {
            float inv = 1.0f / l_i[mi][r];
            int token = b * Sseq + q0 + w * 32 + mi * 16 + kq * 4 + r;
            #pragma unroll
            for (int n = 0; n < 4; ++n)
                aout[(size_t)token * 1024 + h * 64 + n * 16 + rl] = accO[mi][n][r] * inv;
        }
}

// ============================================================================
extern "C" void kernel_launch(void* const* d_in, const int* in_sizes, int n_in,
                              void* d_out, int out_size, void* d_ws, size_t ws_size,
                              hipStream_t stream)
{
    const float* x  = (const float*)d_in[0];
    const float* wq = (const float*)d_in[1];
    const float* bq = (const float*)d_in[2];
    const float* wk = (const float*)d_in[3];
    const float* bk = (const float*)d_in[4];
    const float* wv = (const float*)d_in[5];
    const float* bv = (const float*)d_in[6];
    const float* wo = (const float*)d_in[7];
    const float* bo = (const float*)d_in[8];
    float* out = (float*)d_out;

    // ws: qk_hi 16MB | qk_lo 16MB | vt_hi 8MB | vt_lo 8MB | attn fp32 16MB = 64MB
    const size_t NEED = 67108864;
    if (ws_size < NEED) return;

    char* p = (char*)d_ws;
    ushort* qk_hi = (ushort*)(p);
    ushort* qk_lo = (ushort*)(p + 16777216);
    ushort* vt_hi = (ushort*)(p + 33554432);
    ushort* vt_lo = (ushort*)(p + 41943040);
    float*  attn  = (float*) (p + 50331648);

    // QKV projection, split epilogue (Q scaled by 1/sqrt(64), V transposed).
    gemm_bf16x2<0><<<dim3(24, 32), 256, 0, stream>>>(
        x, wq, wk, wv, bq, bk, bv, nullptr, qk_hi, qk_lo, vt_hi, vt_lo);

    // MFMA causal attention.
    attn_mfma<<<dim3(16, Hh, Bt), 256, 0, stream>>>(
        qk_hi, qk_lo, vt_hi, vt_lo, attn);

    // Output projection (fp32 epilogue straight to d_out).
    gemm_bf16x2<1><<<dim3(8, 32), 256, 0, stream>>>(
        attn, wo, wo, wo, bo, bo, bo, out, nullptr, nullptr, nullptr, nullptr);
}

// Round 7
// 465.848 us; speedup vs baseline: 2.0280x; 1.1558x over previous
//
#include <hip/hip_runtime.h>
#include <hip/hip_bf16.h>
#include <math.h>

// Problem: B=2, S=2048, D=1024, H=16, Hd=64. fp32 in/out.
constexpr int Bt   = 2;
constexpr int Sseq = 2048;
constexpr int Dm   = 1024;
constexpr int Hh   = 16;
constexpr int Mrows = Bt * Sseq;   // 4096
constexpr int Kd    = 1024;        // contraction dim for both GEMMs

typedef __attribute__((ext_vector_type(8))) short bf16x8;   // MFMA A/B frag
typedef __attribute__((ext_vector_type(4))) float f32x4;    // MFMA C/D frag

__device__ __forceinline__ ushort bfhi(float x) {
    __hip_bfloat16 h = __float2bfloat16(x);
    return *reinterpret_cast<ushort*>(&h);
}
__device__ __forceinline__ float bf2f(ushort u) {
    __hip_bfloat16 h;
    *reinterpret_cast<ushort*>(&h) = u;
    return __bfloat162float(h);
}
__device__ __forceinline__ void split2(float x, ushort& h, ushort& l) {
    h = bfhi(x);
    l = bfhi(x - bf2f(h));
}

// ============================================================================
// bf16x2 MFMA GEMM (verified r3/r4): C = A*W^T + bias, 3-term split.
// Tile 128x128, BK=32, 4 waves 2x2, wave 64x64 = 4x4 frags of 16x16x32.
// r6: T14 prefetch — fp32 loads for step k+1 issued after barrier #2,
//     in flight during frag-read + MFMA; only split+ds_write between barriers.
// MODE 0: fused QKV -> split planes (Q pre-scaled, V transposed).
// MODE 1: fp32 epilogue (output projection).
// ============================================================================
template<int MODE>
__global__ __launch_bounds__(256)
void gemm_bf16x2(const float* __restrict__ A,
                 const float* __restrict__ W0, const float* __restrict__ W1,
                 const float* __restrict__ W2,
                 const float* __restrict__ b0, const float* __restrict__ b1,
                 const float* __restrict__ b2,
                 float* __restrict__ Cf,
                 ushort* __restrict__ qk_hi, ushort* __restrict__ qk_lo,
                 ushort* __restrict__ vt_hi, ushort* __restrict__ vt_lo)
{
    __shared__ alignas(16) ushort As[128 * 64];
    __shared__ alignas(16) ushort Bs[128 * 64];

    const int tid = threadIdx.x, lane = tid & 63, w = tid >> 6;

    const int gx = gridDim.x;
    int bid = blockIdx.y * gx + blockIdx.x;
    int cpx = (gx * gridDim.y) >> 3;
    int sb  = (bid & 7) * cpx + (bid >> 3);
    const int m0 = (sb / gx) * 128;
    const int j0 = (sb % gx) * 128;

    const int wsel = j0 >> 10;
    const float* __restrict__ W    = (wsel == 0) ? W0 : ((wsel == 1) ? W1 : W2);
    const float* __restrict__ bias = (wsel == 0) ? b0 : ((wsel == 1) ? b1 : b2);
    const int jj0 = j0 & 1023;

    const int wr = w >> 1, wc = w & 1;
    const int rl = lane & 15, kq = lane >> 4;
    const int sw0 = rl & 7;

    const int srow  = tid >> 1;
    const int khalf = tid & 1;
    const int rsw   = srow & 7;

    const float* ga0 = A + (size_t)(m0  + srow) * Kd + khalf * 16;
    const float* gb0 = W + (size_t)(jj0 + srow) * Kd + khalf * 16;

    f32x4 acc[4][4] = {};
    float av[16], bv[16];

    // Prologue: load k-step 0.
    #pragma unroll
    for (int p = 0; p < 4; ++p) {
        *(float4*)&av[p * 4] = *(const float4*)(ga0 + p * 4);
        *(float4*)&bv[p * 4] = *(const float4*)(gb0 + p * 4);
    }

    for (int k0 = 0; k0 < Kd; k0 += 32) {
        __syncthreads();
        {   // split prefetched regs -> swizzled LDS
            ushort* pa = As + srow * 64;
            ushort* pb = Bs + srow * 64;
            #pragma unroll
            for (int t = 0; t < 2; ++t) {
                bf16x8 hia, loa, hib, lob;
                #pragma unroll
                for (int e = 0; e < 8; ++e) {
                    float xa = av[t * 8 + e], xb = bv[t * 8 + e];
                    ushort ha, la, hb, lb;
                    split2(xa, ha, la); split2(xb, hb, lb);
                    hia[e] = (short)ha; loa[e] = (short)la;
                    hib[e] = (short)hb; lob[e] = (short)lb;
                }
                int s = khalf * 2 + t;
                *(bf16x8*)(pa + ((s    ) ^ rsw) * 8) = hia;
                *(bf16x8*)(pa + ((s + 4) ^ rsw) * 8) = loa;
                *(bf16x8*)(pb + ((s    ) ^ rsw) * 8) = hib;
                *(bf16x8*)(pb + ((s + 4) ^ rsw) * 8) = lob;
            }
        }
        __syncthreads();

        if (k0 + 32 < Kd) {   // T14: next step's loads in flight during MFMA
            #pragma unroll
            for (int p = 0; p < 4; ++p) {
                *(float4*)&av[p * 4] = *(const float4*)(ga0 + k0 + 32 + p * 4);
                *(float4*)&bv[p * 4] = *(const float4*)(gb0 + k0 + 32 + p * 4);
            }
        }

        bf16x8 ah[4], al[4], bh[4], bl[4];
        #pragma unroll
        for (int i = 0; i < 4; ++i) {
            const ushort* pa = As + (wr * 64 + i * 16 + rl) * 64;
            ah[i] = *(const bf16x8*)(pa + ((kq    ) ^ sw0) * 8);
            al[i] = *(const bf16x8*)(pa + ((kq + 4) ^ sw0) * 8);
            const ushort* pb = Bs + (wc * 64 + i * 16 + rl) * 64;
            bh[i] = *(const bf16x8*)(pb + ((kq    ) ^ sw0) * 8);
            bl[i] = *(const bf16x8*)(pb + ((kq + 4) ^ sw0) * 8);
        }
        __builtin_amdgcn_s_setprio(1);
        #pragma unroll
        for (int i = 0; i < 4; ++i)
            #pragma unroll
            for (int j = 0; j < 4; ++j) {
                acc[i][j] = __builtin_amdgcn_mfma_f32_16x16x32_bf16(ah[i], bh[j], acc[i][j], 0, 0, 0);
                acc[i][j] = __builtin_amdgcn_mfma_f32_16x16x32_bf16(ah[i], bl[j], acc[i][j], 0, 0, 0);
                acc[i][j] = __builtin_amdgcn_mfma_f32_16x16x32_bf16(al[i], bh[j], acc[i][j], 0, 0, 0);
            }
        __builtin_amdgcn_s_setprio(0);
    }

    // Epilogue. C/D: col=lane&15, row=(lane>>4)*4+reg (verified).
    #pragma unroll
    for (int i = 0; i < 4; ++i)
        #pragma unroll
        for (int j = 0; j < 4; ++j) {
            int col = j0 + wc * 64 + j * 16 + rl;
            float bv_ = bias[col & 1023];
            int token0 = m0 + wr * 64 + i * 16 + kq * 4;
            if constexpr (MODE == 1) {
                #pragma unroll
                for (int r = 0; r < 4; ++r)
                    Cf[(size_t)(token0 + r) * 1024 + col] = acc[i][j][r] + bv_;
            } else {
                if (col < 2048) {   // Q or K slab
                    float scale = (col < 1024) ? 0.125f : 1.0f;
                    #pragma unroll
                    for (int r = 0; r < 4; ++r) {
                        float val = (acc[i][j][r] + bv_) * scale;
                        ushort hs, ls;
                        split2(val, hs, ls);
                        size_t idx = (size_t)(token0 + r) * 2048 + col;
                        qk_hi[idx] = hs;
                        qk_lo[idx] = ls;
                    }
                } else {            // V slab -> transposed planes
                    int cc = col - 2048;
                    int hh = cc >> 6, dd = cc & 63;
                    int bb = token0 >> 11, s0 = token0 & 2047;
                    ushort hs[4], ls[4];
                    #pragma unroll
                    for (int r = 0; r < 4; ++r)
                        split2(acc[i][j][r] + bv_, hs[r], ls[r]);
                    size_t vrow = ((size_t)(bb * 16 + hh) * 64 + dd) * 2048 + s0;
                    *(ushort4*)(vt_hi + vrow) = make_ushort4(hs[0], hs[1], hs[2], hs[3]);
                    *(ushort4*)(vt_lo + vrow) = make_ushort4(ls[0], ls[1], ls[2], ls[3]);
                }
            }
        }
}

// ============================================================================
// MFMA flash attention (identical to r5 submission):
//  - balanced q-tile launch order (co-resident blocks mix long/short)
//  - T14 prefetch: K/V global->reg issued before compute, ds_write after barrier
//  - T5 setprio around MFMA clusters
// LDS: 32KB K/V + 32KB P = 64KB -> 2 blocks/CU.
// ============================================================================
__global__ __launch_bounds__(256)
void attn_mfma(const ushort* __restrict__ qk_hi, const ushort* __restrict__ qk_lo,
               const ushort* __restrict__ vt_hi, const ushort* __restrict__ vt_lo,
               float* __restrict__ aout)
{
    __shared__ alignas(16) ushort Kh[4096], Kl[4096], Vh[4096], Vl[4096];
    __shared__ alignas(16) uint   P32[4][2048];

    const int xx = blockIdx.x;
    const int qt = (xx & 1) ? (xx >> 1) : (15 - (xx >> 1));
    const int h  = blockIdx.y, b = blockIdx.z;
    const int q0 = qt * 128;
    const int tid = threadIdx.x, lane = tid & 63, w = tid >> 6;
    const int rl = lane & 15, kq = lane >> 4;

    // ---- Q fragments: direct global -> regs (once per block) ----
    bf16x8 qfh[2][2], qfl[2][2];
    {
        const size_t qrow = (size_t)(b * Sseq + q0 + w * 32);
        #pragma unroll
        for (int mi = 0; mi < 2; ++mi)
            #pragma unroll
            for (int s = 0; s < 2; ++s) {
                size_t g = (qrow + mi * 16 + rl) * 2048 + h * 64 + s * 32 + kq * 8;
                qfh[mi][s] = *(const bf16x8*)(qk_hi + g);
                qfl[mi][s] = *(const bf16x8*)(qk_lo + g);
            }
    }

    f32x4 accO[2][4] = {};
    float m_i[2][4], l_i[2][4];
    #pragma unroll
    for (int mi = 0; mi < 2; ++mi)
        #pragma unroll
        for (int r = 0; r < 4; ++r) { m_i[mi][r] = -INFINITY; l_i[mi][r] = 0.0f; }

    const int srow = tid >> 2, sc2 = tid & 3;
    const size_t kbase = (size_t)(b * Sseq) * 2048 + 1024 + h * 64 + sc2 * 16;
    const size_t vbase = ((size_t)((b * 16 + h) * 64) + srow) * 2048 + sc2 * 16;
    const int swA = (sc2 * 2 + 0) ^ (srow & 7);
    const int swB = (sc2 * 2 + 1) ^ (srow & 7);

    bf16x8 stg[8];
    auto ISSUE = [&](int kv0) {
        size_t gk = kbase + (size_t)(kv0 + srow) * 2048;
        size_t gv = vbase + kv0;
        stg[0] = *(const bf16x8*)(qk_hi + gk);
        stg[1] = *(const bf16x8*)(qk_hi + gk + 8);
        stg[2] = *(const bf16x8*)(qk_lo + gk);
        stg[3] = *(const bf16x8*)(qk_lo + gk + 8);
        stg[4] = *(const bf16x8*)(vt_hi + gv);
        stg[5] = *(const bf16x8*)(vt_hi + gv + 8);
        stg[6] = *(const bf16x8*)(vt_lo + gv);
        stg[7] = *(const bf16x8*)(vt_lo + gv + 8);
    };

    const int NT = 2 * qt + 2;
    ISSUE(0);

    for (int kt = 0; kt < NT; ++kt) {
        __syncthreads();
        {
            *(bf16x8*)(Kh + srow * 64 + swA * 8) = stg[0];
            *(bf16x8*)(Kh + srow * 64 + swB * 8) = stg[1];
            *(bf16x8*)(Kl + srow * 64 + swA * 8) = stg[2];
            *(bf16x8*)(Kl + srow * 64 + swB * 8) = stg[3];
            *(bf16x8*)(Vh + srow * 64 + swA * 8) = stg[4];
            *(bf16x8*)(Vh + srow * 64 + swB * 8) = stg[5];
            *(bf16x8*)(Vl + srow * 64 + swA * 8) = stg[6];
            *(bf16x8*)(Vl + srow * 64 + swB * 8) = stg[7];
        }
        __syncthreads();

        if (kt + 1 < NT) ISSUE((kt + 1) * 64);

        const int kv0 = kt * 64;

        // ---- scores: S = Q K^T (3-term) ----
        f32x4 sc[2][4] = {};
        #pragma unroll
        for (int s = 0; s < 2; ++s) {
            bf16x8 kh[4], kl[4];
            #pragma unroll
            for (int n = 0; n < 4; ++n) {
                int row = n * 16 + rl;
                int sw = (s * 4 + kq) ^ (row & 7);
                kh[n] = *(const bf16x8*)(Kh + row * 64 + sw * 8);
                kl[n] = *(const bf16x8*)(Kl + row * 64 + sw * 8);
            }
            __builtin_amdgcn_s_setprio(1);
            #pragma unroll
            for (int mi = 0; mi < 2; ++mi)
                #pragma unroll
                for (int n = 0; n < 4; ++n) {
                    sc[mi][n] = __builtin_amdgcn_mfma_f32_16x16x32_bf16(qfh[mi][s], kh[n], sc[mi][n], 0, 0, 0);
                    sc[mi][n] = __builtin_amdgcn_mfma_f32_16x16x32_bf16(qfh[mi][s], kl[n], sc[mi][n], 0, 0, 0);
                    sc[mi][n] = __builtin_amdgcn_mfma_f32_16x16x32_bf16(qfl[mi][s], kh[n], sc[mi][n], 0, 0, 0);
                }
            __builtin_amdgcn_s_setprio(0);
        }

        if (kt >= 2 * qt) {
            #pragma unroll
            for (int mi = 0; mi < 2; ++mi)
                #pragma unroll
                for (int n = 0; n < 4; ++n)
                    #pragma unroll
                    for (int r = 0; r < 4; ++r)
                        if (kv0 + n * 16 + rl > q0 + w * 32 + mi * 16 + kq * 4 + r)
                            sc[mi][n][r] = -INFINITY;
        }

        // ---- online softmax ----
        float fs[2][4];
        #pragma unroll
        for (int mi = 0; mi < 2; ++mi)
            #pragma unroll
            for (int r = 0; r < 4; ++r) {
                float v = fmaxf(fmaxf(sc[mi][0][r], sc[mi][1][r]),
                                fmaxf(sc[mi][2][r], sc[mi][3][r]));
                v = fmaxf(v, __shfl_xor(v, 1));
                v = fmaxf(v, __shfl_xor(v, 2));
                v = fmaxf(v, __shfl_xor(v, 4));
                v = fmaxf(v, __shfl_xor(v, 8));
                float mnew = fmaxf(m_i[mi][r], v);
                fs[mi][r]  = __expf(m_i[mi][r] - mnew);
                m_i[mi][r] = mnew;
            }

        // ---- P = exp(sc-m): split hi/lo -> swizzled LDS; row-sum ----
        #pragma unroll
        for (int mi = 0; mi < 2; ++mi)
            #pragma unroll
            for (int r = 0; r < 4; ++r) {
                int q = mi * 16 + kq * 4 + r;
                float sum = 0.0f;
                #pragma unroll
                for (int n = 0; n < 4; ++n) {
                    float p = __expf(sc[mi][n][r] - m_i[mi][r]);
                    sum += p;
                    ushort hs, ls;
                    split2(p, hs, ls);
                    int c = n * 4 + (rl >> 2);
                    P32[w][q * 64 + ((c ^ (q & 7)) << 2) + (rl & 3)] =
                        (uint)hs | ((uint)ls << 16);
                }
                sum += __shfl_xor(sum, 1);
                sum += __shfl_xor(sum, 2);
                sum += __shfl_xor(sum, 4);
                sum += __shfl_xor(sum, 8);
                l_i[mi][r] = l_i[mi][r] * fs[mi][r] + sum;
            }

        // ---- rescale O, then O += P V (3-term) ----
        #pragma unroll
        for (int mi = 0; mi < 2; ++mi)
            #pragma unroll
            for (int n = 0; n < 4; ++n)
                #pragma unroll
                for (int r = 0; r < 4; ++r)
                    accO[mi][n][r] *= fs[mi][r];

        #pragma unroll
        for (int s2 = 0; s2 < 2; ++s2) {
            bf16x8 vh[4], vl[4];
            #pragma unroll
            for (int n = 0; n < 4; ++n) {
                int row = n * 16 + rl;
                int sw = (s2 * 4 + kq) ^ (row & 7);
                vh[n] = *(const bf16x8*)(Vh + row * 64 + sw * 8);
                vl[n] = *(const bf16x8*)(Vl + row * 64 + sw * 8);
            }
            #pragma unroll
            for (int mi = 0; mi < 2; ++mi) {
                uint u[8];
                #pragma unroll
                for (int cc = 0; cc < 2; ++cc) {
                    int c = s2 * 8 + kq * 2 + cc;
                    const uint* pp = &P32[w][(mi * 16 + rl) * 64 + ((c ^ (rl & 7)) << 2)];
                    uint4 uu = *(const uint4*)pp;
                    u[cc * 4 + 0] = uu.x; u[cc * 4 + 1] = uu.y;
                    u[cc * 4 + 2] = uu.z; u[cc * 4 + 3] = uu.w;
                }
                uint tph[4], tpl[4];
                #pragma unroll
                for (int jw = 0; jw < 4; ++jw) {
                    tph[jw] = (u[2 * jw] & 0xffffu) | (u[2 * jw + 1] << 16);
                    tpl[jw] = (u[2 * jw] >> 16) | (u[2 * jw + 1] & 0xffff0000u);
                }
                bf16x8 ph = *reinterpret_cast<bf16x8*>(tph);
                bf16x8 pl = *reinterpret_cast<bf16x8*>(tpl);
                __builtin_amdgcn_s_setprio(1);
                #pragma unroll
                for (int n = 0; n < 4; ++n) {
                    accO[mi][n] = __builtin_amdgcn_mfma_f32_16x16x32_bf16(ph, vh[n], accO[mi][n], 0, 0, 0);
                    accO[mi][n] = __builtin_amdgcn_mfma_f32_16x16x32_bf16(ph, vl[n], accO[mi][n], 0, 0, 0);
                    accO[mi][n] = __builtin_amdgcn_mfma_f32_16x16x32_bf16(pl, vh[n], accO[mi][n], 0, 0, 0);
                }
                __builtin_amdgcn_s_setprio(0);
            }
        }
    }

    // ---- epilogue ----
    #pragma unroll
    for (int mi = 0; mi < 2; ++mi)
        #pragma unroll
        for (int r = 0; r < 4; ++r) {
            float inv = 1.0f / l_i[mi][r];
            int token = b * Sseq + q0 + w * 32 + mi * 16 + kq * 4 + r;
            #pragma unroll
            for (int n = 0; n < 4; ++n)
                aout[(size_t)token * 1024 + h * 64 + n * 16 + rl] = accO[mi][n][r] * inv;
        }
}

// ============================================================================
extern "C" void kernel_launch(void* const* d_in, const int* in_sizes, int n_in,
                              void* d_out, int out_size, void* d_ws, size_t ws_size,
                              hipStream_t stream)
{
    const float* x  = (const float*)d_in[0];
    const float* wq = (const float*)d_in[1];
    const float* bq = (const float*)d_in[2];
    const float* wk = (const float*)d_in[3];
    const float* bk = (const float*)d_in[4];
    const float* wv = (const float*)d_in[5];
    const float* bv = (const float*)d_in[6];
    const float* wo = (const float*)d_in[7];
    const float* bo = (const float*)d_in[8];
    float* out = (float*)d_out;

    const size_t NEED = 67108864;   // 64 MiB
    if (ws_size < NEED) return;

    char* p = (char*)d_ws;
    ushort* qk_hi = (ushort*)(p);
    ushort* qk_lo = (ushort*)(p + 16777216);
    ushort* vt_hi = (ushort*)(p + 33554432);
    ushort* vt_lo = (ushort*)(p + 41943040);
    float*  attn  = (float*) (p + 50331648);

    gemm_bf16x2<0><<<dim3(24, 32), 256, 0, stream>>>(
        x, wq, wk, wv, bq, bk, bv, nullptr, qk_hi, qk_lo, vt_hi, vt_lo);

    attn_mfma<<<dim3(16, Hh, Bt), 256, 0, stream>>>(
        qk_hi, qk_lo, vt_hi, vt_lo, attn);

    gemm_bf16x2<1><<<dim3(8, 32), 256, 0, stream>>>(
        attn, wo, wo, wo, bo, bo, bo, out, nullptr, nullptr, nullptr, nullptr);
}

// Round 8
// 429.529 us; speedup vs baseline: 2.1995x; 1.0846x over previous
//
#include <hip/hip_runtime.h>
#include <hip/hip_bf16.h>
#include <math.h>

// Problem: B=2, S=2048, D=1024, H=16, Hd=64. fp32 in/out.
constexpr int Bt   = 2;
constexpr int Sseq = 2048;
constexpr int Dm   = 1024;
constexpr int Hh   = 16;
constexpr int Mrows = Bt * Sseq;   // 4096
constexpr int Kd    = 1024;        // contraction dim for both GEMMs

typedef __attribute__((ext_vector_type(8)))  short bf16x8;   // MFMA A/B frag
typedef __attribute__((ext_vector_type(4)))  float f32x4;    // 16x16 C/D frag
typedef __attribute__((ext_vector_type(16))) float f32x16;   // 32x32 C/D frag

__device__ __forceinline__ ushort bfhi(float x) {
    __hip_bfloat16 h = __float2bfloat16(x);
    return *reinterpret_cast<ushort*>(&h);
}
__device__ __forceinline__ float bf2f(ushort u) {
    __hip_bfloat16 h;
    *reinterpret_cast<ushort*>(&h) = u;
    return __bfloat162float(h);
}
__device__ __forceinline__ void split2(float x, ushort& h, ushort& l) {
    h = bfhi(x);
    l = bfhi(x - bf2f(h));
}

// ============================================================================
// bf16x2 MFMA GEMM (verified r3-r7, unchanged): C = A*W^T + bias, 3-term split.
// ============================================================================
template<int MODE>
__global__ __launch_bounds__(256)
void gemm_bf16x2(const float* __restrict__ A,
                 const float* __restrict__ W0, const float* __restrict__ W1,
                 const float* __restrict__ W2,
                 const float* __restrict__ b0, const float* __restrict__ b1,
                 const float* __restrict__ b2,
                 float* __restrict__ Cf,
                 ushort* __restrict__ qk_hi, ushort* __restrict__ qk_lo,
                 ushort* __restrict__ vt_hi, ushort* __restrict__ vt_lo)
{
    __shared__ alignas(16) ushort As[128 * 64];
    __shared__ alignas(16) ushort Bs[128 * 64];

    const int tid = threadIdx.x, lane = tid & 63, w = tid >> 6;

    const int gx = gridDim.x;
    int bid = blockIdx.y * gx + blockIdx.x;
    int cpx = (gx * gridDim.y) >> 3;
    int sb  = (bid & 7) * cpx + (bid >> 3);
    const int m0 = (sb / gx) * 128;
    const int j0 = (sb % gx) * 128;

    const int wsel = j0 >> 10;
    const float* __restrict__ W    = (wsel == 0) ? W0 : ((wsel == 1) ? W1 : W2);
    const float* __restrict__ bias = (wsel == 0) ? b0 : ((wsel == 1) ? b1 : b2);
    const int jj0 = j0 & 1023;

    const int wr = w >> 1, wc = w & 1;
    const int rl = lane & 15, kq = lane >> 4;
    const int sw0 = rl & 7;

    const int srow  = tid >> 1;
    const int khalf = tid & 1;
    const int rsw   = srow & 7;

    const float* ga0 = A + (size_t)(m0  + srow) * Kd + khalf * 16;
    const float* gb0 = W + (size_t)(jj0 + srow) * Kd + khalf * 16;

    f32x4 acc[4][4] = {};
    float av[16], bv[16];

    #pragma unroll
    for (int p = 0; p < 4; ++p) {
        *(float4*)&av[p * 4] = *(const float4*)(ga0 + p * 4);
        *(float4*)&bv[p * 4] = *(const float4*)(gb0 + p * 4);
    }

    for (int k0 = 0; k0 < Kd; k0 += 32) {
        __syncthreads();
        {
            ushort* pa = As + srow * 64;
            ushort* pb = Bs + srow * 64;
            #pragma unroll
            for (int t = 0; t < 2; ++t) {
                bf16x8 hia, loa, hib, lob;
                #pragma unroll
                for (int e = 0; e < 8; ++e) {
                    float xa = av[t * 8 + e], xb = bv[t * 8 + e];
                    ushort ha, la, hb, lb;
                    split2(xa, ha, la); split2(xb, hb, lb);
                    hia[e] = (short)ha; loa[e] = (short)la;
                    hib[e] = (short)hb; lob[e] = (short)lb;
                }
                int s = khalf * 2 + t;
                *(bf16x8*)(pa + ((s    ) ^ rsw) * 8) = hia;
                *(bf16x8*)(pa + ((s + 4) ^ rsw) * 8) = loa;
                *(bf16x8*)(pb + ((s    ) ^ rsw) * 8) = hib;
                *(bf16x8*)(pb + ((s + 4) ^ rsw) * 8) = lob;
            }
        }
        __syncthreads();

        if (k0 + 32 < Kd) {
            #pragma unroll
            for (int p = 0; p < 4; ++p) {
                *(float4*)&av[p * 4] = *(const float4*)(ga0 + k0 + 32 + p * 4);
                *(float4*)&bv[p * 4] = *(const float4*)(gb0 + k0 + 32 + p * 4);
            }
        }

        bf16x8 ah[4], al[4], bh[4], bl[4];
        #pragma unroll
        for (int i = 0; i < 4; ++i) {
            const ushort* pa = As + (wr * 64 + i * 16 + rl) * 64;
            ah[i] = *(const bf16x8*)(pa + ((kq    ) ^ sw0) * 8);
            al[i] = *(const bf16x8*)(pa + ((kq + 4) ^ sw0) * 8);
            const ushort* pb = Bs + (wc * 64 + i * 16 + rl) * 64;
            bh[i] = *(const bf16x8*)(pb + ((kq    ) ^ sw0) * 8);
            bl[i] = *(const bf16x8*)(pb + ((kq + 4) ^ sw0) * 8);
        }
        __builtin_amdgcn_s_setprio(1);
        #pragma unroll
        for (int i = 0; i < 4; ++i)
            #pragma unroll
            for (int j = 0; j < 4; ++j) {
                acc[i][j] = __builtin_amdgcn_mfma_f32_16x16x32_bf16(ah[i], bh[j], acc[i][j], 0, 0, 0);
                acc[i][j] = __builtin_amdgcn_mfma_f32_16x16x32_bf16(ah[i], bl[j], acc[i][j], 0, 0, 0);
                acc[i][j] = __builtin_amdgcn_mfma_f32_16x16x32_bf16(al[i], bh[j], acc[i][j], 0, 0, 0);
            }
        __builtin_amdgcn_s_setprio(0);
    }

    #pragma unroll
    for (int i = 0; i < 4; ++i)
        #pragma unroll
        for (int j = 0; j < 4; ++j) {
            int col = j0 + wc * 64 + j * 16 + rl;
            float bv_ = bias[col & 1023];
            int token0 = m0 + wr * 64 + i * 16 + kq * 4;
            if constexpr (MODE == 1) {
                #pragma unroll
                for (int r = 0; r < 4; ++r)
                    Cf[(size_t)(token0 + r) * 1024 + col] = acc[i][j][r] + bv_;
            } else {
                if (col < 2048) {
                    float scale = (col < 1024) ? 0.125f : 1.0f;
                    #pragma unroll
                    for (int r = 0; r < 4; ++r) {
                        float val = (acc[i][j][r] + bv_) * scale;
                        ushort hs, ls;
                        split2(val, hs, ls);
                        size_t idx = (size_t)(token0 + r) * 2048 + col;
                        qk_hi[idx] = hs;
                        qk_lo[idx] = ls;
                    }
                } else {
                    int cc = col - 2048;
                    int hh = cc >> 6, dd = cc & 63;
                    int bb = token0 >> 11, s0 = token0 & 2047;
                    ushort hs[4], ls[4];
                    #pragma unroll
                    for (int r = 0; r < 4; ++r)
                        split2(acc[i][j][r] + bv_, hs[r], ls[r]);
                    size_t vrow = ((size_t)(bb * 16 + hh) * 64 + dd) * 2048 + s0;
                    *(ushort4*)(vt_hi + vrow) = make_ushort4(hs[0], hs[1], hs[2], hs[3]);
                    *(ushort4*)(vt_lo + vrow) = make_ushort4(ls[0], ls[1], ls[2], ls[3]);
                }
            }
        }
}

// ============================================================================
// r8: 32x32 swapped-QK^T flash attention (§B structure), bf16x2 3-term.
//  - QK^T: mfma32(A=K, B=Q) -> lane owns one q (col=lane&31): softmax is
//    31 in-lane ops + ONE shfl_xor(32) per reduce (no 32-shfl chains).
//  - P kept in registers (packed bf16 pairs); A-frag halves exchanged with
//    partner lane (lane^32) via shfl_xor(32): P-LDS roundtrip eliminated.
//  - PV: mfma32(A=V^T, B=P) computes O^T -> accO q-index == lane's q:
//    rescale + epilogue lane-local.
//  - K/V staging + T14 reg prefetch identical to r7. LDS 32KB.
// C/D 32x32 layout (verified m74/m101): col=lane&31, row=(r&3)+8*(r>>2)+4*(lane>>5)
// ============================================================================
__global__ __launch_bounds__(256)
void attn_mfma32(const ushort* __restrict__ qk_hi, const ushort* __restrict__ qk_lo,
                 const ushort* __restrict__ vt_hi, const ushort* __restrict__ vt_lo,
                 float* __restrict__ aout)
{
    __shared__ alignas(16) ushort Kh[4096], Kl[4096], Vh[4096], Vl[4096];

    const int xx = blockIdx.x;
    const int qt = (xx & 1) ? (xx >> 1) : (15 - (xx >> 1));
    const int h  = blockIdx.y, b = blockIdx.z;
    const int q0 = qt * 128;
    const int tid = threadIdx.x, l = tid & 63, w = tid >> 6;
    const int lo5 = l & 31, hi = l >> 5;

    // ---- Q frags (B-operand): Q[q=lo5][d = s*16 + hi*8 + e], once ----
    bf16x8 qh[4], ql[4];
    {
        const size_t qrow = (size_t)(b * Sseq + q0 + w * 32 + lo5);
        #pragma unroll
        for (int s = 0; s < 4; ++s) {
            size_t g = qrow * 2048 + h * 64 + s * 16 + hi * 8;
            qh[s] = *(const bf16x8*)(qk_hi + g);
            ql[s] = *(const bf16x8*)(qk_lo + g);
        }
    }

    f32x16 accO[2] = {};            // [nd]: lane holds O[q=lo5][d=crow(r,hi)+32nd]
    float m_r = -INFINITY, l_r = 0.0f;
    const int qg = q0 + w * 32 + lo5;

    // ---- staging (identical to r7): thread -> (row=tid>>2, c2=tid&3) ----
    const int srow = tid >> 2, sc2 = tid & 3;
    const size_t kbase = (size_t)(b * Sseq) * 2048 + 1024 + h * 64 + sc2 * 16;
    const size_t vbase = ((size_t)((b * 16 + h) * 64) + srow) * 2048 + sc2 * 16;
    const int swA = (sc2 * 2 + 0) ^ (srow & 7);
    const int swB = (sc2 * 2 + 1) ^ (srow & 7);

    bf16x8 stg[8];
    auto ISSUE = [&](int kv0) {
        size_t gk = kbase + (size_t)(kv0 + srow) * 2048;
        size_t gv = vbase + kv0;
        stg[0] = *(const bf16x8*)(qk_hi + gk);
        stg[1] = *(const bf16x8*)(qk_hi + gk + 8);
        stg[2] = *(const bf16x8*)(qk_lo + gk);
        stg[3] = *(const bf16x8*)(qk_lo + gk + 8);
        stg[4] = *(const bf16x8*)(vt_hi + gv);
        stg[5] = *(const bf16x8*)(vt_hi + gv + 8);
        stg[6] = *(const bf16x8*)(vt_lo + gv);
        stg[7] = *(const bf16x8*)(vt_lo + gv + 8);
    };

    const int NT = 2 * qt + 2;
    ISSUE(0);

    for (int kt = 0; kt < NT; ++kt) {
        __syncthreads();
        {
            *(bf16x8*)(Kh + srow * 64 + swA * 8) = stg[0];
            *(bf16x8*)(Kh + srow * 64 + swB * 8) = stg[1];
            *(bf16x8*)(Kl + srow * 64 + swA * 8) = stg[2];
            *(bf16x8*)(Kl + srow * 64 + swB * 8) = stg[3];
            *(bf16x8*)(Vh + srow * 64 + swA * 8) = stg[4];
            *(bf16x8*)(Vh + srow * 64 + swB * 8) = stg[5];
            *(bf16x8*)(Vl + srow * 64 + swA * 8) = stg[6];
            *(bf16x8*)(Vl + srow * 64 + swB * 8) = stg[7];
        }
        __syncthreads();

        if (kt + 1 < NT) ISSUE((kt + 1) * 64);   // T14: in flight during compute

        const int kv0 = kt * 64;

        // ---- QK^T swapped: sc[n] = K(n) . Q, 3-term ----
        f32x16 sc[2] = {};
        #pragma unroll
        for (int s = 0; s < 4; ++s) {
            __builtin_amdgcn_s_setprio(1);
            #pragma unroll
            for (int n = 0; n < 2; ++n) {
                int row = n * 32 + lo5;
                int sl = (s * 2 + hi) ^ (row & 7);
                bf16x8 kh = *(const bf16x8*)(Kh + row * 64 + sl * 8);
                bf16x8 kl = *(const bf16x8*)(Kl + row * 64 + sl * 8);
                sc[n] = __builtin_amdgcn_mfma_f32_32x32x16_bf16(kh, qh[s], sc[n], 0, 0, 0);
                sc[n] = __builtin_amdgcn_mfma_f32_32x32x16_bf16(kh, ql[s], sc[n], 0, 0, 0);
                sc[n] = __builtin_amdgcn_mfma_f32_32x32x16_bf16(kl, qh[s], sc[n], 0, 0, 0);
            }
            __builtin_amdgcn_s_setprio(0);
        }

        // ---- causal mask: kv = kv0 + n*32 + crow(r,hi); q = qg ----
        if (kt >= 2 * qt) {
            #pragma unroll
            for (int n = 0; n < 2; ++n)
                #pragma unroll
                for (int r = 0; r < 16; ++r) {
                    int kv = kv0 + n * 32 + ((r & 3) + 8 * (r >> 2) + 4 * hi);
                    if (kv > qg) sc[n][r] = -INFINITY;
                }
        }

        // ---- online softmax: lane owns q=lo5; halves merge via shfl_xor(32) ----
        float vmax = -INFINITY;
        #pragma unroll
        for (int n = 0; n < 2; ++n)
            #pragma unroll
            for (int r = 0; r < 16; ++r)
                vmax = fmaxf(vmax, sc[n][r]);
        vmax = fmaxf(vmax, __shfl_xor(vmax, 32));
        float mnew = fmaxf(m_r, vmax);
        float fs = __expf(m_r - mnew);
        m_r = mnew;

        // P = exp(sc - m), split hi/lo, pack r-pairs into u32
        uint phk[2][8], plk[2][8];
        float sum = 0.0f;
        #pragma unroll
        for (int n = 0; n < 2; ++n)
            #pragma unroll
            for (int j = 0; j < 8; ++j) {
                float p0 = __expf(sc[n][2 * j]     - mnew);
                float p1 = __expf(sc[n][2 * j + 1] - mnew);
                sum += p0 + p1;
                ushort h0, l0, h1, l1;
                split2(p0, h0, l0);
                split2(p1, h1, l1);
                phk[n][j] = (uint)h0 | ((uint)h1 << 16);
                plk[n][j] = (uint)l0 | ((uint)l1 << 16);
            }
        sum += __shfl_xor(sum, 32);
        l_r = l_r * fs + sum;

        #pragma unroll
        for (int nd = 0; nd < 2; ++nd)
            #pragma unroll
            for (int r = 0; r < 16; ++r)
                accO[nd][r] *= fs;

        // ---- PV: O^T += V^T . P (3-term); P A-frag built in-register ----
        #pragma unroll
        for (int step = 0; step < 4; ++step) {
            const int n  = step >> 1;
            const int io = (step & 1) * 4 + hi * 2;        // own u32 pair idx
            const int is = (step & 1) * 4 + (1 - hi) * 2;  // partner pair idx
            uint oh0 = phk[n][io], oh1 = phk[n][io + 1];
            uint ol0 = plk[n][io], ol1 = plk[n][io + 1];
            uint sh0 = (uint)__shfl_xor((int)phk[n][is],     32);
            uint sh1 = (uint)__shfl_xor((int)phk[n][is + 1], 32);
            uint sl0 = (uint)__shfl_xor((int)plk[n][is],     32);
            uint sl1 = (uint)__shfl_xor((int)plk[n][is + 1], 32);
            uint fh[4], fl[4];
            if (hi) { fh[0] = sh0; fh[1] = sh1; fh[2] = oh0; fh[3] = oh1;
                      fl[0] = sl0; fl[1] = sl1; fl[2] = ol0; fl[3] = ol1; }
            else    { fh[0] = oh0; fh[1] = oh1; fh[2] = sh0; fh[3] = sh1;
                      fl[0] = ol0; fl[1] = ol1; fl[2] = sl0; fl[3] = sl1; }
            bf16x8 ph = *reinterpret_cast<bf16x8*>(fh);
            bf16x8 pl = *reinterpret_cast<bf16x8*>(fl);

            __builtin_amdgcn_s_setprio(1);
            #pragma unroll
            for (int nd = 0; nd < 2; ++nd) {
                int row = nd * 32 + lo5;
                int sl_ = (step * 2 + hi) ^ (row & 7);
                bf16x8 vh = *(const bf16x8*)(Vh + row * 64 + sl_ * 8);
                bf16x8 vl = *(const bf16x8*)(Vl + row * 64 + sl_ * 8);
                accO[nd] = __builtin_amdgcn_mfma_f32_32x32x16_bf16(vh, ph, accO[nd], 0, 0, 0);
                accO[nd] = __builtin_amdgcn_mfma_f32_32x32x16_bf16(vh, pl, accO[nd], 0, 0, 0);
                accO[nd] = __builtin_amdgcn_mfma_f32_32x32x16_bf16(vl, ph, accO[nd], 0, 0, 0);
            }
            __builtin_amdgcn_s_setprio(0);
        }
    }

    // ---- epilogue: O[q=lo5][d = 8*rg + 4*hi + 32*nd + (0..3)] ----
    {
        float inv = 1.0f / l_r;
        const size_t token = (size_t)(b * Sseq + q0 + w * 32 + lo5);
        #pragma unroll
        for (int nd = 0; nd < 2; ++nd)
            #pragma unroll
            for (int rg = 0; rg < 4; ++rg) {
                float4 o = { accO[nd][4 * rg + 0] * inv, accO[nd][4 * rg + 1] * inv,
                             accO[nd][4 * rg + 2] * inv, accO[nd][4 * rg + 3] * inv };
                *(float4*)&aout[token * 1024 + h * 64 + nd * 32 + 8 * rg + 4 * hi] = o;
            }
    }
}

// ============================================================================
extern "C" void kernel_launch(void* const* d_in, const int* in_sizes, int n_in,
                              void* d_out, int out_size, void* d_ws, size_t ws_size,
                              hipStream_t stream)
{
    const float* x  = (const float*)d_in[0];
    const float* wq = (const float*)d_in[1];
    const float* bq = (const float*)d_in[2];
    const float* wk = (const float*)d_in[3];
    const float* bk = (const float*)d_in[4];
    const float* wv = (const float*)d_in[5];
    const float* bv = (const float*)d_in[6];
    const float* wo = (const float*)d_in[7];
    const float* bo = (const float*)d_in[8];
    float* out = (float*)d_out;

    const size_t NEED = 67108864;   // 64 MiB
    if (ws_size < NEED) return;

    char* p = (char*)d_ws;
    ushort* qk_hi = (ushort*)(p);
    ushort* qk_lo = (ushort*)(p + 16777216);
    ushort* vt_hi = (ushort*)(p + 33554432);
    ushort* vt_lo = (ushort*)(p + 41943040);
    float*  attn  = (float*) (p + 50331648);

    gemm_bf16x2<0><<<dim3(24, 32), 256, 0, stream>>>(
        x, wq, wk, wv, bq, bk, bv, nullptr, qk_hi, qk_lo, vt_hi, vt_lo);

    attn_mfma32<<<dim3(16, Hh, Bt), 256, 0, stream>>>(
        qk_hi, qk_lo, vt_hi, vt_lo, attn);

    gemm_bf16x2<1><<<dim3(8, 32), 256, 0, stream>>>(
        attn, wo, wo, wo, bo, bo, bo, out, nullptr, nullptr, nullptr, nullptr);
}